// Round 14
// baseline (234.206 us; speedup 1.0000x reference)
//
#include <hip/hip_runtime.h>
#include <math.h>

// Problem constants (fixed by reference)
#define Bsz   4
#define Tsz   2048
#define Dsz   1024
#define Hsz   16
#define Lsz   64
#define BHsz  64          // B*H
#define CH    64          // chunk length
#define NCH   32          // T / CH
#define QKVLD 3072        // qkv row stride (3*D)
#define SCL   0.125f      // 1/sqrt(64)
#define QSC   512.0f      // qs prescale (avoid fp16 subnormals); undone in epilogue
#define QSCI  (1.0f/512.0f)

typedef float  floatx4 __attribute__((ext_vector_type(4)));
typedef _Float16 half8 __attribute__((ext_vector_type(8)));
typedef _Float16 half4v __attribute__((ext_vector_type(4)));
typedef _Float16 half2v __attribute__((ext_vector_type(2)));

#define AS1 __attribute__((address_space(1)))
#define AS3 __attribute__((address_space(3)))

static __device__ __forceinline__ void gload_lds16(const void* g, void* l) {
  __builtin_amdgcn_global_load_lds((const AS1 unsigned int*)g,
                                   (AS3 unsigned int*)l, 16, 0, 0);
}

static __device__ __forceinline__ float wave_sum64(float v) {
#pragma unroll
  for (int off = 1; off < 64; off <<= 1) v += __shfl_xor(v, off);
  return v;
}

// ---------------------------------------------------------------------------
// Fused prep: blocks [0,8192) conv x; [8192,11264) conv w; [11264,12288) w_out^T
// ---------------------------------------------------------------------------
__launch_bounds__(256)
__global__ void prep(const float* __restrict__ x, _Float16* __restrict__ xh,
                     const float* __restrict__ w, _Float16* __restrict__ wh,
                     const float* __restrict__ wo, _Float16* __restrict__ woT) {
  const int blk = blockIdx.x, tid = threadIdx.x;
  if (blk < 11264) {
    const float* in  = (blk < 8192) ? x : w;
    _Float16*   outp = (blk < 8192) ? xh : wh;
    const int bi = (blk < 8192) ? blk : blk - 8192;
    const int i = (bi * 256 + tid) * 4;
    float4 v = *(const float4*)(in + i);
    half4v h = { (_Float16)v.x, (_Float16)v.y, (_Float16)v.z, (_Float16)v.w };
    *(half4v*)(outp + i) = h;
  } else {
    __shared__ float tile[32][33];
    const int bi = blk - 11264;
    const int bx = (bi & 31) * 32;   // n-offset
    const int by = (bi >> 5) * 32;   // k-offset
    const int tx = tid & 31, ty0 = tid >> 5;
#pragma unroll
    for (int p = 0; p < 4; p++) {
      const int ty = ty0 + p * 8;
      tile[ty][tx] = wo[(size_t)(by + ty) * 1024 + bx + tx];
    }
    __syncthreads();
#pragma unroll
    for (int p = 0; p < 4; p++) {
      const int ty = ty0 + p * 8;
      woT[(size_t)(bx + ty) * 1024 + by + tx] = (_Float16)tile[tx][ty];
    }
  }
}

// ---------------------------------------------------------------------------
// QKV GEMM round-14: GEMM2's 128x128/BK=32/4-wave dbuf counted-vmcnt schedule
// (r7-measured ~860 TF on GEMM2 — ABOVE the 256^2 kernel's 640-700 TF)
// transplanted to M=8192 N=3072 K=1024. Mechanism: 32 KB LDS -> 4-5 blocks/CU
// of cross-block TLP, which the 128-KB 256^2 structure (1 blk/CU, MfmaUtil
// pinned 27-28% over 5 variants) cannot have. Register ledger = gemm2's
// (acc 64 + frags 32 + addr ~30, no launch-bounds clamp -> no r6-style spill).
// Grid 1536 = 8 XCD x 8 m-tiles x 24 n-tiles (bijective; 2 MB A band per XCD).
// Frag layout at 64 B rows is conflict-free without swizzle (r6/r7-validated).
// vmcnt ledger: 8 -> (w4) 4 -> 8, never drains to 0 (r7-validated liveness).
// Trailing prefetches (kt=32,33) read <=64 elems past xh/wh row ends into the
// adjacent workspace arrays (in-allocation) and land in dead LDS only.
// Epilogue: C fp16 + fused kexp for n0 in [1024,2048) (128-wide tiles nest
// inside the 1024-wide q/k/v regions -> block-uniform predicate).
// ---------------------------------------------------------------------------
__launch_bounds__(256)
__global__ void qkv_gemm(const _Float16* __restrict__ A, const _Float16* __restrict__ B,
                         _Float16* __restrict__ C) {
  __shared__ __align__(16) _Float16 As[2][128][32];   // 16 KB
  __shared__ __align__(16) _Float16 Bs[2][128][32];   // 16 KB
  const int tid = threadIdx.x;
  const int wv = tid >> 6, lane = tid & 63;
  const int wm = wv >> 1, wn = wv & 1;
  const int fr = lane & 15, fq = lane >> 4;

  const int flat = blockIdx.x;
  const int xcd = flat & 7, loc = flat >> 3;      // 1536 = 8 x 192
  const int m0 = (xcd * 8 + loc / 24) * 128;      // m-tiles [8*xcd, 8*xcd+8)
  const int n0 = (loc % 24) * 128;

  const int srow = lane >> 2;          // 0..15
  const int scg  = lane & 3;           // 16B col-group
  const _Float16* aSrc = A + (size_t)(m0 + wv * 32 + srow) * 1024 + scg * 8;
  const _Float16* bSrc = B + (size_t)(n0 + wv * 32 + srow) * 1024 + scg * 8;
  _Float16* aBase = &As[0][0][0];
  _Float16* bBase = &Bs[0][0][0];

  const _Float16* apt = aBase + (wm * 64 + fr) * 32 + fq * 8;
  const _Float16* bpt = bBase + (wn * 64 + fr) * 32 + fq * 8;

  floatx4 acc[4][4];
#pragma unroll
  for (int i = 0; i < 4; i++)
#pragma unroll
    for (int j = 0; j < 4; j++) acc[i][j] = (floatx4){0.f, 0.f, 0.f, 0.f};

  half8 aF[4], bF[4];

#define BAR2() do { __builtin_amdgcn_s_barrier();                              \
                    asm volatile("" ::: "memory"); } while (0)
#define VMW4() asm volatile("s_waitcnt vmcnt(4)" ::: "memory")
#define SYNC() do { __builtin_amdgcn_s_barrier();                              \
    asm volatile("s_waitcnt lgkmcnt(0)" ::: "memory");                         \
    __builtin_amdgcn_sched_barrier(0); } while (0)

#define STAGE(kt, bufi) do {                                                   \
    const _Float16* sa_ = aSrc + (size_t)(kt) * 32;                            \
    const _Float16* sb_ = bSrc + (size_t)(kt) * 32;                            \
    gload_lds16(sa_,             aBase + (bufi) * 4096 + (wv * 32) * 32 + lane * 8);      \
    gload_lds16(sa_ + 16 * 1024, aBase + (bufi) * 4096 + (wv * 32 + 16) * 32 + lane * 8); \
    gload_lds16(sb_,             bBase + (bufi) * 4096 + (wv * 32) * 32 + lane * 8);      \
    gload_lds16(sb_ + 16 * 1024, bBase + (bufi) * 4096 + (wv * 32 + 16) * 32 + lane * 8); \
  } while (0)

#define RD8(bufi) do {                                                         \
    _Pragma("unroll")                                                          \
    for (int mf = 0; mf < 4; mf++)                                             \
      aF[mf] = *(const half8*)(apt + (bufi) * 4096 + mf * 512);                \
    _Pragma("unroll")                                                          \
    for (int nf = 0; nf < 4; nf++)                                             \
      bF[nf] = *(const half8*)(bpt + (bufi) * 4096 + nf * 512);                \
  } while (0)

#define MM16() do {                                                            \
    __builtin_amdgcn_s_setprio(1);                                             \
    _Pragma("unroll")                                                          \
    for (int mt = 0; mt < 4; mt++)                                             \
      _Pragma("unroll")                                                        \
      for (int nt = 0; nt < 4; nt++)                                           \
        acc[mt][nt] = __builtin_amdgcn_mfma_f32_16x16x32_f16(aF[mt], bF[nt],   \
                                                             acc[mt][nt], 0, 0, 0); \
    __builtin_amdgcn_s_setprio(0);                                             \
  } while (0)

  // prologue: tile0 -> buf0, tile1 -> buf1; retire tile0; sync.
  STAGE(0, 0);
  STAGE(1, 1);
  VMW4(); BAR2();

  // 32 K-tiles (K=1024, BK=32), 2 per iteration.
#pragma unroll 1
  for (int t = 0; t < 32; t += 2) {
    RD8(0);
    SYNC(); MM16(); BAR2();
    STAGE(t + 2, 0);               // outstanding {t+1, t+2} = 8
    VMW4();                        // retires t+1
    BAR2();

    RD8(1);
    SYNC(); MM16(); BAR2();
    STAGE(t + 3, 1);               // outstanding {t+2, t+3} = 8
    VMW4();                        // retires t+2
    BAR2();
  }

#undef MM16
#undef RD8
#undef STAGE
#undef SYNC
#undef VMW4
#undef BAR2

  // epilogue: C fp16 with fused kexp for the k-region (block-uniform)
  const bool kreg = (n0 >= 1024) && (n0 < 2048);
#pragma unroll
  for (int mt = 0; mt < 4; mt++) {
    const int row = m0 + wm * 64 + mt * 16 + fq * 4;
#pragma unroll
    for (int nt = 0; nt < 4; nt++) {
      const int col = n0 + wn * 64 + nt * 16 + fr;
#pragma unroll
      for (int r = 0; r < 4; r++) {
        float v = acc[mt][nt][r];
        if (kreg) v = __expf(v * SCL) + 1e-6f;
        C[(size_t)(row + r) * 3072 + col] = (_Float16)v;
      }
    }
  }
}

// ---------------------------------------------------------------------------
// GEMM2: 128x128 tile, BK=32, 4 waves, dbuf + counted vmcnt (r7-validated).
// ---------------------------------------------------------------------------
__launch_bounds__(256)
__global__ void gemm2(const _Float16* __restrict__ A, const _Float16* __restrict__ B,
                      float* __restrict__ C) {
  __shared__ __align__(16) _Float16 As[2][128][32];
  __shared__ __align__(16) _Float16 Bs[2][128][32];
  const int tid = threadIdx.x;
  const int wv = tid >> 6, lane = tid & 63;
  const int wm = wv >> 1, wn = wv & 1;
  const int fr = lane & 15, fq = lane >> 4;

  const int flat = blockIdx.x;
  const int xcd = flat & 7, loc = flat >> 3;
  const int m0 = (xcd * 8 + (loc >> 3)) * 128;
  const int n0 = (loc & 7) * 128;

  const int srow = lane >> 2;
  const int scg  = lane & 3;
  const _Float16* aSrc = A + (size_t)(m0 + wv * 32 + srow) * 1024 + scg * 8;
  const _Float16* bSrc = B + (size_t)(n0 + wv * 32 + srow) * 1024 + scg * 8;
  _Float16* aBase = &As[0][0][0];
  _Float16* bBase = &Bs[0][0][0];

  const _Float16* apt = aBase + (wm * 64 + fr) * 32 + fq * 8;
  const _Float16* bpt = bBase + (wn * 64 + fr) * 32 + fq * 8;

  floatx4 acc[4][4];
#pragma unroll
  for (int i = 0; i < 4; i++)
#pragma unroll
    for (int j = 0; j < 4; j++) acc[i][j] = (floatx4){0.f, 0.f, 0.f, 0.f};

  half8 aF[4], bF[4];

#define BAR2() do { __builtin_amdgcn_s_barrier();                              \
                    asm volatile("" ::: "memory"); } while (0)
#define VMW4() asm volatile("s_waitcnt vmcnt(4)" ::: "memory")
#define SYNC() do { __builtin_amdgcn_s_barrier();                              \
    asm volatile("s_waitcnt lgkmcnt(0)" ::: "memory");                         \
    __builtin_amdgcn_sched_barrier(0); } while (0)

#define STAGE(kt, bufi) do {                                                   \
    const _Float16* sa_ = aSrc + (size_t)(kt) * 32;                            \
    const _Float16* sb_ = bSrc + (size_t)(kt) * 32;                            \
    gload_lds16(sa_,             aBase + (bufi) * 4096 + (wv * 32) * 32 + lane * 8);      \
    gload_lds16(sa_ + 16 * 1024, aBase + (bufi) * 4096 + (wv * 32 + 16) * 32 + lane * 8); \
    gload_lds16(sb_,             bBase + (bufi) * 4096 + (wv * 32) * 32 + lane * 8);      \
    gload_lds16(sb_ + 16 * 1024, bBase + (bufi) * 4096 + (wv * 32 + 16) * 32 + lane * 8); \
  } while (0)

#define RD8(bufi) do {                                                         \
    _Pragma("unroll")                                                          \
    for (int mf = 0; mf < 4; mf++)                                             \
      aF[mf] = *(const half8*)(apt + (bufi) * 4096 + mf * 512);                \
    _Pragma("unroll")                                                          \
    for (int nf = 0; nf < 4; nf++)                                             \
      bF[nf] = *(const half8*)(bpt + (bufi) * 4096 + nf * 512);                \
  } while (0)

#define MM16() do {                                                            \
    __builtin_amdgcn_s_setprio(1);                                             \
    _Pragma("unroll")                                                          \
    for (int mt = 0; mt < 4; mt++)                                             \
      _Pragma("unroll")                                                        \
      for (int nt = 0; nt < 4; nt++)                                           \
        acc[mt][nt] = __builtin_amdgcn_mfma_f32_16x16x32_f16(aF[mt], bF[nt],   \
                                                             acc[mt][nt], 0, 0, 0); \
    __builtin_amdgcn_s_setprio(0);                                             \
  } while (0)

  STAGE(0, 0);
  STAGE(1, 1);
  VMW4(); BAR2();

#pragma unroll 1
  for (int t = 0; t < 32; t += 2) {
    RD8(0);
    SYNC(); MM16(); BAR2();
    STAGE(t + 2, 0);
    VMW4();
    BAR2();

    RD8(1);
    SYNC(); MM16(); BAR2();
    STAGE(t + 3, 1);
    VMW4();
    BAR2();
  }

#undef MM16
#undef RD8
#undef STAGE
#undef SYNC
#undef VMW4
#undef BAR2

#pragma unroll
  for (int mt = 0; mt < 4; mt++) {
    const int row = m0 + wm * 64 + mt * 16 + fq * 4;
#pragma unroll
    for (int nt = 0; nt < 4; nt++) {
      const int col = n0 + wn * 64 + nt * 16 + fr;
#pragma unroll
      for (int r = 0; r < 4; r++)
        C[(size_t)(row + r) * 1024 + col] = acc[mt][nt][r];
    }
  }
}

// ---------------------------------------------------------------------------
// chunk_kv: 2048 blocks x 1 chunk each (r13, measured equal-best). KV fp16.
// ---------------------------------------------------------------------------
__launch_bounds__(256)
__global__ void chunk_kv(const _Float16* __restrict__ qkv, _Float16* __restrict__ KV,
                         float* __restrict__ Ksum) {
  const int blk = blockIdx.x;              // 0..2047
  const int bh = blk >> 5, c = blk & 31;
  const int b = bh >> 4, h = bh & 15;
  const int tid = threadIdx.x;
  const int wave = tid >> 6, lane = tid & 63;
  const int fr = lane & 15, fq = lane >> 4;
  const int m2  = (tid & 31) * 2;     // column index pair (l or m)
  const int tg8 = (tid >> 5) * 8;     // t-group of 8

  __shared__ __align__(16) _Float16 KxT[64][72];   // kexp^T [l][t]
  __shared__ __align__(16) _Float16 VT [64][72];   // V^T    [m][t]

  const size_t base = ((size_t)(b * Tsz + c * CH)) * QKVLD + h * 64;
  half8 klo, khi, vlo, vhi;
#pragma unroll
  for (int j = 0; j < 8; j++) {
    const int t = tg8 + j;
    half2v kk = *(const half2v*)(qkv + base + (size_t)t * QKVLD + 1024 + m2);
    klo[j] = kk[0]; khi[j] = kk[1];
    half2v vv = *(const half2v*)(qkv + base + (size_t)t * QKVLD + 2048 + m2);
    vlo[j] = vv[0]; vhi[j] = vv[1];
  }
  *(half8*)&KxT[m2][tg8]     = klo;
  *(half8*)&KxT[m2 + 1][tg8] = khi;
  *(half8*)&VT[m2][tg8]      = vlo;
  *(half8*)&VT[m2 + 1][tg8]  = vhi;
  __syncthreads();

  floatx4 acc[4];
#pragma unroll
  for (int j = 0; j < 4; j++) acc[j] = (floatx4){0.f, 0.f, 0.f, 0.f};
#pragma unroll
  for (int ks = 0; ks < 2; ks++) {
    half8 av = *(const half8*)&VT[wave * 16 + fr][ks * 32 + fq * 8];
#pragma unroll
    for (int j = 0; j < 4; j++) {
      half8 bv = *(const half8*)&KxT[j * 16 + fr][ks * 32 + fq * 8];
      acc[j] = __builtin_amdgcn_mfma_f32_16x16x32_f16(av, bv, acc[j], 0, 0, 0);
    }
  }
  _Float16* KVp = KV + ((size_t)(bh * NCH + c)) * 4096;
#pragma unroll
  for (int j = 0; j < 4; j++)
#pragma unroll
    for (int r = 0; r < 4; r++)
      KVp[(wave * 16 + fq * 4 + r) * 64 + j * 16 + fr] = (_Float16)acc[j][r];

  if (tid < 64) {
    float s = 0.f;
    const half8* row = (const half8*)&KxT[tid][0];
#pragma unroll
    for (int j8 = 0; j8 < 8; j8++) {
      half8 v8 = row[j8];
#pragma unroll
      for (int j = 0; j < 8; j++) s += (float)v8[j];
    }
    Ksum[(bh * NCH + c) * 64 + tid] = s;
  }
}

// ---------------------------------------------------------------------------
// prefix_kern: 512 blocks, one fp16 half2v chain/thread (r13). fp32 run-sum.
// ---------------------------------------------------------------------------
__launch_bounds__(256)
__global__ void prefix_kern(_Float16* __restrict__ KV, float* __restrict__ Ksum) {
  const int cid = blockIdx.x * 256 + threadIdx.x;   // 0..131071
  const int bh = cid >> 11, e2 = cid & 2047;        // half2v chain per thread
  half2v* p = (half2v*)(KV + (size_t)bh * NCH * 4096) + e2;
  float ax = 0.f, ay = 0.f;
#pragma unroll
  for (int c = 0; c < NCH; c++) {
    half2v t = p[(size_t)c * 2048];
    half2v o = { (_Float16)ax, (_Float16)ay };
    p[(size_t)c * 2048] = o;
    ax += (float)t[0]; ay += (float)t[1];
  }
  if (cid < 1024) {                                 // Ksum float4 chains
    const int kbh = cid >> 4, l4 = cid & 15;
    float4* kp = (float4*)(Ksum + (size_t)kbh * NCH * 64) + l4;
    float4 acc = {0.f, 0.f, 0.f, 0.f};
#pragma unroll
    for (int c = 0; c < NCH; c++) {
      float4 t = kp[c * 16];
      kp[c * 16] = acc;
      acc.x += t.x; acc.y += t.y; acc.z += t.z; acc.w += t.w;
    }
  }
}

// ---------------------------------------------------------------------------
// chunk_y v7 (r10-verified): fp16 KV straight copy; no-max softmax.
// grid (BH, NCH), 256 threads (4 waves).
// ---------------------------------------------------------------------------
__launch_bounds__(256)
__global__ void chunk_y(const _Float16* __restrict__ qkv, const _Float16* __restrict__ KV,
                        const float* __restrict__ Ksum, _Float16* __restrict__ Y) {
  const int bh = blockIdx.x, c = blockIdx.y;
  const int b = bh >> 4, h = bh & 15;
  const int tid = threadIdx.x;
  const int wave = tid >> 6, lane = tid & 63;
  const int fr = lane & 15, fq = lane >> 4;

  __shared__ __align__(16) _Float16 kxh[64][72];   // kexp [s][l]; later Y tile
  __shared__ __align__(16) _Float16 kxT[64][72];   // kexp^T [l][t]; later kninv [t][l]
  __shared__ __align__(16) _Float16 Ph[64][136];   // P0: [64:128]=V rows; then [Qs|A]
  __shared__ __align__(16) _Float16 Bh[64][136];   // [Sp^T | V^T]

  const size_t base = ((size_t)(b * Tsz + c * CH)) * QKVLD + h * 64;
  const _Float16* KVp = KV + ((size_t)(bh * NCH + c)) * 4096;
  const int ksoff = (bh * NCH + c) * 64;

  _Float16 qreg[16];
#pragma unroll
  for (int i = 0; i < 16; i++)
    qreg[i] = qkv[base + (size_t)(wave * 16 + i) * QKVLD + lane];

  float ksb[4];
#pragma unroll
  for (int j = 0; j < 4; j++) ksb[j] = Ksum[ksoff + j * 16 + fr];

  // ---- P0: coalesced row loads ----
  {
    const int rr  = tid >> 3;            // 0..31
    const int sg8 = (tid & 7) * 8;       // 0..56
#pragma unroll
    for (int p = 0; p < 2; p++) {
      const int t = p * 32 + rr;
      *(half8*)&kxh[t][sg8] =
          *(const half8*)(qkv + base + (size_t)t * QKVLD + 1024 + sg8);
      *(half8*)&Ph[t][64 + sg8] =
          *(const half8*)(qkv + base + (size_t)t * QKVLD + 2048 + sg8);
    }
  }
  // Sp^T rows (fp16, straight copy)
  {
    const int m  = tid >> 2;             // 0..63
    const int l0 = (tid & 3) * 16;       // 0,16,32,48
    *(half8*)&Bh[m][l0]     = *(const half8*)(KVp + m * 64 + l0);
    *(half8*)&Bh[m][l0 + 8] = *(const half8*)(KVp + m * 64 + l0 + 8);
  }
  __syncthreads();

  // ---- T: LDS transposes (b32 column reads, lane=col -> conflict-free) ----
  {
    const int l2  = (tid & 31) * 2;      // even column pair
    const int tg8 = (tid >> 5) * 8;      // 8-row group
    half8 k0, k1, v0, v1;
#pragma unroll
    for (int j = 0; j < 8; j++) {
      const int t = tg8 + j;
      half2v kk = *(const half2v*)&kxh[t][l2];
      k0[j] = kk[0]; k1[j] = kk[1];
      half2v vv = *(const half2v*)&Ph[t][64 + l2];
      v0[j] = vv[0]; v1[j] = vv[1];
    }
    *(half8*)&kxT[l2][tg8]          = k0;
    *(half8*)&kxT[l2 + 1][tg8]      = k1;
    *(half8*)&Bh[l2][64 + tg8]      = v0;
    *(half8*)&Bh[l2 + 1][64 + tg8]  = v1;
  }
  __syncthreads();

  // ---- P1: inclusive cumsum over t via tri-MFMA: kn = L . Kx ----
  {
    floatx4 kacc[4];
#pragma unroll
    for (int j = 0; j < 4; j++) kacc[j] = (floatx4){0.f, 0.f, 0.f, 0.f};
#pragma unroll
    for (int ks = 0; ks < 2; ks++) {
      half8 af;
#pragma unroll
      for (int j = 0; j < 8; j++)
        af[j] = (ks * 32 + fq * 8 + j) <= (wave * 16 + fr) ? (_Float16)1.0f
                                                           : (_Float16)0.0f;
#pragma unroll
      for (int j = 0; j < 4; j++) {
        half8 bf = *(const half8*)&kxT[j * 16 + fr][ks * 32 + fq * 8];
        kacc[j] = __builtin_amdgcn_mfma_f32_16x16x32_f16(af, bf, kacc[j], 0, 0, 0);
      }
    }
    __syncthreads();   // all kxT reads done -> safe to overwrite with kninv
#pragma unroll
    for (int j = 0; j < 4; j++)
#pragma unroll
      for (int r = 0; r < 4; r++)
        kxT[wave * 16 + fq * 4 + r][j * 16 + fr] =
            (_Float16)(QSC / (ksb[j] + kacc[j][r]));
  }
  // no barrier: P2 reads only this wave's own kninv strip

  // ---- P2: softmax * kninv -> Ph[:,0:64] (no-max variant) ----
#pragma unroll
  for (int i = 0; i < 16; i++) {
    const int t = wave * 16 + i;
    float e = __expf((float)qreg[i] * SCL);
    float s = wave_sum64(e);
    Ph[t][lane] = (_Float16)((e / s) * (float)kxT[t][lane]);
  }
  __syncthreads();

  // ---- P3: scores A = Qs . Kx^T (NT), causal mask, -> Ph[:,64:128] ----
  const int wm = (wave >> 1) * 32, wn = (wave & 1) * 32;
  {
    floatx4 a2[2][2];
#pragma unroll
    for (int mt = 0; mt < 2; mt++)
#pragma unroll
      for (int nt = 0; nt < 2; nt++) a2[mt][nt] = (floatx4){0.f, 0.f, 0.f, 0.f};
#pragma unroll
    for (int ks = 0; ks < 2; ks++) {
      half8 af[2], bf[2];
#pragma unroll
      for (int i = 0; i < 2; i++) {
        af[i] = *(const half8*)&Ph[wm + i * 16 + fr][ks * 32 + fq * 8];
        bf[i] = *(const half8*)&kxh[wn + i * 16 + fr][ks * 32 + fq * 8];
      }
#pragma unroll
      for (int mt = 0; mt < 2; mt++)
#pragma unroll
        for (int nt = 0; nt < 2; nt++)
          a2[mt][nt] = __builtin_amdgcn_mfma_f32_16x16x32_f16(af[mt], bf[nt], a2[mt][nt], 0, 0, 0);
    }
#pragma unroll
    for (int mt = 0; mt < 2; mt++)
#pragma unroll
      for (int nt = 0; nt < 2; nt++)
#pragma unroll
        for (int r = 0; r < 4; r++) {
          const int t = wm + mt * 16 + fq * 4 + r;
          const int s = wn + nt * 16 + fr;
          Ph[t][64 + s] = (_Float16)(s <= t ? a2[mt][nt][r] : 0.f);
        }
  }
  __syncthreads();

  // ---- P4: Y = [Qs|A] . [Sp^T|V^T]^T (NT, K=128); stage into kxh ----
  {
    floatx4 acc[2][2];
#pragma unroll
    for (int mt = 0; mt < 2; mt++)
#pragma unroll
      for (int nt = 0; nt < 2; nt++) acc[mt][nt] = (floatx4){0.f, 0.f, 0.f, 0.f};
#pragma unroll
    for (int ks = 0; ks < 4; ks++) {
      half8 af[2], bf[2];
#pragma unroll
      for (int i = 0; i < 2; i++) {
        af[i] = *(const half8*)&Ph[wm + i * 16 + fr][ks * 32 + fq * 8];
        bf[i] = *(const half8*)&Bh[wn + i * 16 + fr][ks * 32 + fq * 8];
      }
#pragma unroll
      for (int mt = 0; mt < 2; mt++)
#pragma unroll
        for (int nt = 0; nt < 2; nt++)
          acc[mt][nt] = __builtin_amdgcn_mfma_f32_16x16x32_f16(af[mt], bf[nt], acc[mt][nt], 0, 0, 0);
    }
#pragma unroll
    for (int mt = 0; mt < 2; mt++)
#pragma unroll
      for (int nt = 0; nt < 2; nt++)
#pragma unroll
        for (int r = 0; r < 4; r++)
          kxh[wm + mt * 16 + fq * 4 + r][wn + nt * 16 + fr] =
              (_Float16)(acc[mt][nt][r] * QSCI);
  }
  __syncthreads();

  // coalesced store: 4 threads cover one 128 B row
  {
    const int ty = tid >> 2, sg = (tid & 3) * 16;
    _Float16* yrow = Y + (size_t)(b * Tsz + c * CH + ty) * Dsz + h * 64 + sg;
    *(half8*)(yrow)     = *(const half8*)&kxh[ty][sg];
    *(half8*)(yrow + 8) = *(const half8*)&kxh[ty][sg + 8];
  }
}

// ---------------------------------------------------------------------------
extern "C" void kernel_launch(void* const* d_in, const int* in_sizes, int n_in,
                              void* d_out, int out_size, void* d_ws, size_t ws_size,
                              hipStream_t stream) {
  const float* x     = (const float*)d_in[0];   // (4,2048,1024)
  const float* w     = (const float*)d_in[1];   // (3072,1024)
  const float* w_out = (const float*)d_in[2];   // (1024,1024)
  float* out = (float*)d_out;                   // (4,2048,1024)

  _Float16* xh   = (_Float16*)d_ws;                  // 8192*1024
  _Float16* Yh   = xh;                               // alias (xh dead after GEMM1)
  _Float16* wh   = xh + (size_t)8192 * 1024;         // 3072*1024
  _Float16* woT  = wh + (size_t)3072 * 1024;         // 1024*1024
  _Float16* qkvh = woT + (size_t)1024 * 1024;        // 8192*3072 fp16 (k-region = kexp)
  _Float16* KV   = qkvh + (size_t)8192 * 3072;       // 64*32*4096 fp16 (S^T/prefix)
  float* Ksum = (float*)(KV + (size_t)BHsz * NCH * 4096);  // 64*32*64 fp32

  // 0) fused dtype prep
  prep<<<12288, 256, 0, stream>>>(x, xh, w, wh, w_out, woT);

  // 1) qkv = x @ w.T — 128² dbuf counted-vmcnt schedule, grid 1536, 4-5 blk/CU
  qkv_gemm<<<1536, 256, 0, stream>>>(xh, wh, qkvh);

  // 2) chunked scan (KV fp16)
  chunk_kv<<<2048, 256, 0, stream>>>(qkvh, KV, Ksum);
  prefix_kern<<<512, 256, 0, stream>>>(KV, Ksum);
  chunk_y<<<dim3(BHsz, NCH), 256, 0, stream>>>(qkvh, KV, Ksum, Yh);

  // 3) out = y @ w_out — dbuf counted-vmcnt 128² schedule
  gemm2<<<512, 256, 0, stream>>>(Yh, woT, out);
}

// Round 15
// 229.796 us; speedup vs baseline: 1.0192x; 1.0192x over previous
//
#include <hip/hip_runtime.h>
#include <math.h>

// Problem constants (fixed by reference)
#define Bsz   4
#define Tsz   2048
#define Dsz   1024
#define Hsz   16
#define Lsz   64
#define BHsz  64          // B*H
#define CH    64          // chunk length
#define NCH   32          // T / CH
#define QKVLD 3072        // qkv row stride (3*D)
#define SCL   0.125f      // 1/sqrt(64)
#define QSC   512.0f      // qs prescale (avoid fp16 subnormals); undone in epilogue
#define QSCI  (1.0f/512.0f)

typedef float  floatx4 __attribute__((ext_vector_type(4)));
typedef _Float16 half8 __attribute__((ext_vector_type(8)));
typedef _Float16 half4v __attribute__((ext_vector_type(4)));
typedef _Float16 half2v __attribute__((ext_vector_type(2)));

#define AS1 __attribute__((address_space(1)))
#define AS3 __attribute__((address_space(3)))

static __device__ __forceinline__ void gload_lds16(const void* g, void* l) {
  __builtin_amdgcn_global_load_lds((const AS1 unsigned int*)g,
                                   (AS3 unsigned int*)l, 16, 0, 0);
}

static __device__ __forceinline__ float wave_sum64(float v) {
#pragma unroll
  for (int off = 1; off < 64; off <<= 1) v += __shfl_xor(v, off);
  return v;
}

// ---------------------------------------------------------------------------
// Fused prep: blocks [0,8192) conv x; [8192,11264) conv w; [11264,12288) w_out^T
// ---------------------------------------------------------------------------
__launch_bounds__(256)
__global__ void prep(const float* __restrict__ x, _Float16* __restrict__ xh,
                     const float* __restrict__ w, _Float16* __restrict__ wh,
                     const float* __restrict__ wo, _Float16* __restrict__ woT) {
  const int blk = blockIdx.x, tid = threadIdx.x;
  if (blk < 11264) {
    const float* in  = (blk < 8192) ? x : w;
    _Float16*   outp = (blk < 8192) ? xh : wh;
    const int bi = (blk < 8192) ? blk : blk - 8192;
    const int i = (bi * 256 + tid) * 4;
    float4 v = *(const float4*)(in + i);
    half4v h = { (_Float16)v.x, (_Float16)v.y, (_Float16)v.z, (_Float16)v.w };
    *(half4v*)(outp + i) = h;
  } else {
    __shared__ float tile[32][33];
    const int bi = blk - 11264;
    const int bx = (bi & 31) * 32;   // n-offset
    const int by = (bi >> 5) * 32;   // k-offset
    const int tx = tid & 31, ty0 = tid >> 5;
#pragma unroll
    for (int p = 0; p < 4; p++) {
      const int ty = ty0 + p * 8;
      tile[ty][tx] = wo[(size_t)(by + ty) * 1024 + bx + tx];
    }
    __syncthreads();
#pragma unroll
    for (int p = 0; p < 4; p++) {
      const int ty = ty0 + p * 8;
      woT[(size_t)(bx + ty) * 1024 + by + tx] = (_Float16)tile[tx][ty];
    }
  }
}

// ---------------------------------------------------------------------------
// QKV GEMM: 256x256 tile, BK=64, 8 waves, 8-thin-phase counted-vmcnt schedule
// (r2 version; verified 71.7-75.2 us across 7 runs; VGPR 116, no spill).
// PLATEAU NOTE: six structure variants (48-read thin, 24-read thin, 24-read
// fat, BK=32 2blk/CU [spilled], 128x256 no-tail, 128^2 4-5blk/CU) all land
// at 72-77 us / MfmaUtil 27-30% regardless of occupancy or bank conflicts.
// The binding constraint is this schedule family's per-K-tile barrier+vmcnt
// phase floor, not LDS/occupancy/packing — frozen at the best variant.
// ---------------------------------------------------------------------------
__launch_bounds__(512, 2)
__global__ void qkv_gemm8(const _Float16* __restrict__ A, const _Float16* __restrict__ B,
                          _Float16* __restrict__ C) {
  __shared__ __align__(16) _Float16 AsF[2 * 256 * 64];   // 64 KB
  __shared__ __align__(16) _Float16 BsF[2 * 256 * 64];   // 64 KB
  const int tid  = threadIdx.x;
  const int wv   = tid >> 6, lane = tid & 63;
  const int wm   = wv >> 2, wn = wv & 3;
  const int fr   = lane & 15, fq = lane >> 4;

  const int flat = blockIdx.x;
  const int g  = (flat & 7) * 48 + (flat >> 3);
  const int m0 = (g / 12) * 256;
  const int n0 = (g % 12) * 256;

  const int srow = lane >> 3;
  const int scg  = (lane & 7) ^ srow;
  const int wv8  = wv * 8;
  const _Float16* aSrc = A + (size_t)(m0 + wv8 + srow) * 1024 + scg * 8;
  const _Float16* bSrc = B + (size_t)(n0 + wv8 + srow) * 1024 + scg * 8;

  const int sw  = fr & 7;
  const int ck0 = ((0 + fq) ^ sw) * 8;
  const int ck1 = ((4 + fq) ^ sw) * 8;
  const _Float16* apt = AsF + (wm * 64 + fr) * 64;
  const _Float16* bpt = BsF + (wn * 32 + fr) * 64;

  floatx4 acc[8][4];
#pragma unroll
  for (int i = 0; i < 8; i++)
#pragma unroll
    for (int j = 0; j < 4; j++) acc[i][j] = (floatx4){0.f, 0.f, 0.f, 0.f};

  half8 aF[8];
  half8 bF0[4], bF1[4];

#define BAR2() do { __builtin_amdgcn_s_barrier();                              \
                    asm volatile("" ::: "memory"); } while (0)
#define VMW4() asm volatile("s_waitcnt vmcnt(4)" ::: "memory")
#define SYNC() do { __builtin_amdgcn_s_barrier();                              \
    asm volatile("s_waitcnt lgkmcnt(0)" ::: "memory");                         \
    __builtin_amdgcn_sched_barrier(0); } while (0)

#define STAGE_A(kt, hm, sbuf) do {                                             \
    const _Float16* s_ = aSrc + (hm) * (128 * 1024) + (kt) * 64;               \
    gload_lds16(s_,             &AsF[(sbuf) * 16384 + ((hm) * 128 + wv8) * 64]);      \
    gload_lds16(s_ + 64 * 1024, &AsF[(sbuf) * 16384 + ((hm) * 128 + 64 + wv8) * 64]); \
  } while (0)
#define STAGE_B(kt, hm, sbuf) do {                                             \
    const _Float16* s_ = bSrc + (hm) * (128 * 1024) + (kt) * 64;               \
    gload_lds16(s_,             &BsF[(sbuf) * 16384 + ((hm) * 128 + wv8) * 64]);      \
    gload_lds16(s_ + 64 * 1024, &BsF[(sbuf) * 16384 + ((hm) * 128 + 64 + wv8) * 64]); \
  } while (0)

#define RD_A(buf, qm) do {                                                     \
    _Pragma("unroll")                                                          \
    for (int mf = 0; mf < 4; mf++) {                                           \
      const _Float16* p_ = apt + (buf) * 16384 + (qm) * 8192 + mf * 1024;      \
      aF[mf * 2]     = *(const half8*)(p_ + ck0);                              \
      aF[mf * 2 + 1] = *(const half8*)(p_ + ck1);                              \
    } } while (0)
#define RD_B(buf, qn, dst) do {                                                \
    _Pragma("unroll")                                                          \
    for (int nf = 0; nf < 2; nf++) {                                           \
      const _Float16* p_ = bpt + (buf) * 16384 + (qn) * 8192 + nf * 1024;      \
      dst[nf * 2]     = *(const half8*)(p_ + ck0);                             \
      dst[nf * 2 + 1] = *(const half8*)(p_ + ck1);                             \
    } } while (0)

#define MM(qm, qn, bb) do {                                                    \
    __builtin_amdgcn_s_setprio(1);                                             \
    _Pragma("unroll")                                                          \
    for (int mf = 0; mf < 4; mf++)                                             \
      _Pragma("unroll")                                                        \
      for (int nf = 0; nf < 2; nf++) {                                         \
        acc[(qm) * 4 + mf][(qn) * 2 + nf] = __builtin_amdgcn_mfma_f32_16x16x32_f16( \
            aF[mf * 2], bb[nf * 2], acc[(qm) * 4 + mf][(qn) * 2 + nf], 0, 0, 0);     \
        acc[(qm) * 4 + mf][(qn) * 2 + nf] = __builtin_amdgcn_mfma_f32_16x16x32_f16( \
            aF[mf * 2 + 1], bb[nf * 2 + 1], acc[(qm) * 4 + mf][(qn) * 2 + nf], 0, 0, 0); \
      }                                                                        \
    __builtin_amdgcn_s_setprio(0);                                             \
  } while (0)

  STAGE_A(0, 0, 0); STAGE_B(0, 0, 0); STAGE_A(0, 1, 0); STAGE_B(0, 1, 0);
  STAGE_A(1, 0, 1); STAGE_B(1, 0, 1);
  VMW4(); BAR2();

#pragma unroll 1
  for (int t = 0; t < 16; t += 2) {
    RD_A(0, 0); RD_B(0, 0, bF0); STAGE_A(t + 1, 1, 1);
    SYNC(); MM(0, 0, bF0); BAR2();

    RD_B(0, 1, bF1); STAGE_B(t + 1, 1, 1); STAGE_A(t + 2, 0, 0);
    SYNC(); MM(0, 1, bF1); BAR2();

    RD_A(0, 1); STAGE_B(t + 2, 0, 0);
    SYNC(); MM(1, 1, bF1); BAR2();

    VMW4();
    SYNC(); MM(1, 0, bF0); BAR2();

    RD_A(1, 0); RD_B(1, 0, bF0); STAGE_A(t + 2, 1, 0);
    SYNC(); MM(0, 0, bF0); BAR2();

    RD_B(1, 1, bF1); STAGE_B(t + 2, 1, 0); STAGE_A(t + 3, 0, 1);
    SYNC(); MM(0, 1, bF1); BAR2();

    RD_A(1, 1); STAGE_B(t + 3, 0, 1);
    SYNC(); MM(1, 1, bF1); BAR2();

    VMW4();
    SYNC(); MM(1, 0, bF0); BAR2();
  }

#undef MM
#undef RD_B
#undef RD_A
#undef STAGE_B
#undef STAGE_A
#undef SYNC
#undef VMW4
#undef BAR2

  const bool kreg = (n0 >= 1024) && (n0 < 2048);
#pragma unroll
  for (int qm = 0; qm < 2; qm++)
#pragma unroll
    for (int mf = 0; mf < 4; mf++) {
      const int row = m0 + qm * 128 + wm * 64 + mf * 16 + fq * 4;
#pragma unroll
      for (int qn = 0; qn < 2; qn++)
#pragma unroll
        for (int nf = 0; nf < 2; nf++) {
          const int col = n0 + qn * 128 + wn * 32 + nf * 16 + fr;
#pragma unroll
          for (int r = 0; r < 4; r++) {
            float v = acc[qm * 4 + mf][qn * 2 + nf][r];
            if (kreg) v = __expf(v * SCL) + 1e-6f;
            C[(size_t)(row + r) * 3072 + col] = (_Float16)v;
          }
        }
    }
}

// ---------------------------------------------------------------------------
// GEMM2: 128x128 tile, BK=32, 4 waves, dbuf + counted vmcnt (r7-validated).
// ---------------------------------------------------------------------------
__launch_bounds__(256)
__global__ void gemm2(const _Float16* __restrict__ A, const _Float16* __restrict__ B,
                      float* __restrict__ C) {
  __shared__ __align__(16) _Float16 As[2][128][32];
  __shared__ __align__(16) _Float16 Bs[2][128][32];
  const int tid = threadIdx.x;
  const int wv = tid >> 6, lane = tid & 63;
  const int wm = wv >> 1, wn = wv & 1;
  const int fr = lane & 15, fq = lane >> 4;

  const int flat = blockIdx.x;
  const int xcd = flat & 7, loc = flat >> 3;
  const int m0 = (xcd * 8 + (loc >> 3)) * 128;
  const int n0 = (loc & 7) * 128;

  const int srow = lane >> 2;
  const int scg  = lane & 3;
  const _Float16* aSrc = A + (size_t)(m0 + wv * 32 + srow) * 1024 + scg * 8;
  const _Float16* bSrc = B + (size_t)(n0 + wv * 32 + srow) * 1024 + scg * 8;
  _Float16* aBase = &As[0][0][0];
  _Float16* bBase = &Bs[0][0][0];

  const _Float16* apt = aBase + (wm * 64 + fr) * 32 + fq * 8;
  const _Float16* bpt = bBase + (wn * 64 + fr) * 32 + fq * 8;

  floatx4 acc[4][4];
#pragma unroll
  for (int i = 0; i < 4; i++)
#pragma unroll
    for (int j = 0; j < 4; j++) acc[i][j] = (floatx4){0.f, 0.f, 0.f, 0.f};

  half8 aF[4], bF[4];

#define BAR2() do { __builtin_amdgcn_s_barrier();                              \
                    asm volatile("" ::: "memory"); } while (0)
#define VMW4() asm volatile("s_waitcnt vmcnt(4)" ::: "memory")
#define SYNC() do { __builtin_amdgcn_s_barrier();                              \
    asm volatile("s_waitcnt lgkmcnt(0)" ::: "memory");                         \
    __builtin_amdgcn_sched_barrier(0); } while (0)

#define STAGE(kt, bufi) do {                                                   \
    const _Float16* sa_ = aSrc + (size_t)(kt) * 32;                            \
    const _Float16* sb_ = bSrc + (size_t)(kt) * 32;                            \
    gload_lds16(sa_,             aBase + (bufi) * 4096 + (wv * 32) * 32 + lane * 8);      \
    gload_lds16(sa_ + 16 * 1024, aBase + (bufi) * 4096 + (wv * 32 + 16) * 32 + lane * 8); \
    gload_lds16(sb_,             bBase + (bufi) * 4096 + (wv * 32) * 32 + lane * 8);      \
    gload_lds16(sb_ + 16 * 1024, bBase + (bufi) * 4096 + (wv * 32 + 16) * 32 + lane * 8); \
  } while (0)

#define RD8(bufi) do {                                                         \
    _Pragma("unroll")                                                          \
    for (int mf = 0; mf < 4; mf++)                                             \
      aF[mf] = *(const half8*)(apt + (bufi) * 4096 + mf * 512);                \
    _Pragma("unroll")                                                          \
    for (int nf = 0; nf < 4; nf++)                                             \
      bF[nf] = *(const half8*)(bpt + (bufi) * 4096 + nf * 512);                \
  } while (0)

#define MM16() do {                                                            \
    __builtin_amdgcn_s_setprio(1);                                             \
    _Pragma("unroll")                                                          \
    for (int mt = 0; mt < 4; mt++)                                             \
      _Pragma("unroll")                                                        \
      for (int nt = 0; nt < 4; nt++)                                           \
        acc[mt][nt] = __builtin_amdgcn_mfma_f32_16x16x32_f16(aF[mt], bF[nt],   \
                                                             acc[mt][nt], 0, 0, 0); \
    __builtin_amdgcn_s_setprio(0);                                             \
  } while (0)

  STAGE(0, 0);
  STAGE(1, 1);
  VMW4(); BAR2();

#pragma unroll 1
  for (int t = 0; t < 32; t += 2) {
    RD8(0);
    SYNC(); MM16(); BAR2();
    STAGE(t + 2, 0);
    VMW4();
    BAR2();

    RD8(1);
    SYNC(); MM16(); BAR2();
    STAGE(t + 3, 1);
    VMW4();
    BAR2();
  }

#undef MM16
#undef RD8
#undef STAGE
#undef SYNC
#undef VMW4
#undef BAR2

#pragma unroll
  for (int mt = 0; mt < 4; mt++) {
    const int row = m0 + wm * 64 + mt * 16 + fq * 4;
#pragma unroll
    for (int nt = 0; nt < 4; nt++) {
      const int col = n0 + wn * 64 + nt * 16 + fr;
#pragma unroll
      for (int r = 0; r < 4; r++)
        C[(size_t)(row + r) * 1024 + col] = acc[mt][nt][r];
    }
  }
}

// ---------------------------------------------------------------------------
// chunk_kv: 2048 blocks x 1 chunk each (r13, measured equal-best). KV fp16.
// ---------------------------------------------------------------------------
__launch_bounds__(256)
__global__ void chunk_kv(const _Float16* __restrict__ qkv, _Float16* __restrict__ KV,
                         float* __restrict__ Ksum) {
  const int blk = blockIdx.x;              // 0..2047
  const int bh = blk >> 5, c = blk & 31;
  const int b = bh >> 4, h = bh & 15;
  const int tid = threadIdx.x;
  const int wave = tid >> 6, lane = tid & 63;
  const int fr = lane & 15, fq = lane >> 4;
  const int m2  = (tid & 31) * 2;     // column index pair (l or m)
  const int tg8 = (tid >> 5) * 8;     // t-group of 8

  __shared__ __align__(16) _Float16 KxT[64][72];   // kexp^T [l][t]
  __shared__ __align__(16) _Float16 VT [64][72];   // V^T    [m][t]

  const size_t base = ((size_t)(b * Tsz + c * CH)) * QKVLD + h * 64;
  half8 klo, khi, vlo, vhi;
#pragma unroll
  for (int j = 0; j < 8; j++) {
    const int t = tg8 + j;
    half2v kk = *(const half2v*)(qkv + base + (size_t)t * QKVLD + 1024 + m2);
    klo[j] = kk[0]; khi[j] = kk[1];
    half2v vv = *(const half2v*)(qkv + base + (size_t)t * QKVLD + 2048 + m2);
    vlo[j] = vv[0]; vhi[j] = vv[1];
  }
  *(half8*)&KxT[m2][tg8]     = klo;
  *(half8*)&KxT[m2 + 1][tg8] = khi;
  *(half8*)&VT[m2][tg8]      = vlo;
  *(half8*)&VT[m2 + 1][tg8]  = vhi;
  __syncthreads();

  floatx4 acc[4];
#pragma unroll
  for (int j = 0; j < 4; j++) acc[j] = (floatx4){0.f, 0.f, 0.f, 0.f};
#pragma unroll
  for (int ks = 0; ks < 2; ks++) {
    half8 av = *(const half8*)&VT[wave * 16 + fr][ks * 32 + fq * 8];
#pragma unroll
    for (int j = 0; j < 4; j++) {
      half8 bv = *(const half8*)&KxT[j * 16 + fr][ks * 32 + fq * 8];
      acc[j] = __builtin_amdgcn_mfma_f32_16x16x32_f16(av, bv, acc[j], 0, 0, 0);
    }
  }
  _Float16* KVp = KV + ((size_t)(bh * NCH + c)) * 4096;
#pragma unroll
  for (int j = 0; j < 4; j++)
#pragma unroll
    for (int r = 0; r < 4; r++)
      KVp[(wave * 16 + fq * 4 + r) * 64 + j * 16 + fr] = (_Float16)acc[j][r];

  if (tid < 64) {
    float s = 0.f;
    const half8* row = (const half8*)&KxT[tid][0];
#pragma unroll
    for (int j8 = 0; j8 < 8; j8++) {
      half8 v8 = row[j8];
#pragma unroll
      for (int j = 0; j < 8; j++) s += (float)v8[j];
    }
    Ksum[(bh * NCH + c) * 64 + tid] = s;
  }
}

// ---------------------------------------------------------------------------
// prefix_kern: 512 blocks, one fp16 half2v chain/thread (r13). fp32 run-sum.
// ---------------------------------------------------------------------------
__launch_bounds__(256)
__global__ void prefix_kern(_Float16* __restrict__ KV, float* __restrict__ Ksum) {
  const int cid = blockIdx.x * 256 + threadIdx.x;   // 0..131071
  const int bh = cid >> 11, e2 = cid & 2047;        // half2v chain per thread
  half2v* p = (half2v*)(KV + (size_t)bh * NCH * 4096) + e2;
  float ax = 0.f, ay = 0.f;
#pragma unroll
  for (int c = 0; c < NCH; c++) {
    half2v t = p[(size_t)c * 2048];
    half2v o = { (_Float16)ax, (_Float16)ay };
    p[(size_t)c * 2048] = o;
    ax += (float)t[0]; ay += (float)t[1];
  }
  if (cid < 1024) {                                 // Ksum float4 chains
    const int kbh = cid >> 4, l4 = cid & 15;
    float4* kp = (float4*)(Ksum + (size_t)kbh * NCH * 64) + l4;
    float4 acc = {0.f, 0.f, 0.f, 0.f};
#pragma unroll
    for (int c = 0; c < NCH; c++) {
      float4 t = kp[c * 16];
      kp[c * 16] = acc;
      acc.x += t.x; acc.y += t.y; acc.z += t.z; acc.w += t.w;
    }
  }
}

// ---------------------------------------------------------------------------
// chunk_y v7 (r10-verified): fp16 KV straight copy; no-max softmax.
// grid (BH, NCH), 256 threads (4 waves).
// ---------------------------------------------------------------------------
__launch_bounds__(256)
__global__ void chunk_y(const _Float16* __restrict__ qkv, const _Float16* __restrict__ KV,
                        const float* __restrict__ Ksum, _Float16* __restrict__ Y) {
  const int bh = blockIdx.x, c = blockIdx.y;
  const int b = bh >> 4, h = bh & 15;
  const int tid = threadIdx.x;
  const int wave = tid >> 6, lane = tid & 63;
  const int fr = lane & 15, fq = lane >> 4;

  __shared__ __align__(16) _Float16 kxh[64][72];   // kexp [s][l]; later Y tile
  __shared__ __align__(16) _Float16 kxT[64][72];   // kexp^T [l][t]; later kninv [t][l]
  __shared__ __align__(16) _Float16 Ph[64][136];   // P0: [64:128]=V rows; then [Qs|A]
  __shared__ __align__(16) _Float16 Bh[64][136];   // [Sp^T | V^T]

  const size_t base = ((size_t)(b * Tsz + c * CH)) * QKVLD + h * 64;
  const _Float16* KVp = KV + ((size_t)(bh * NCH + c)) * 4096;
  const int ksoff = (bh * NCH + c) * 64;

  _Float16 qreg[16];
#pragma unroll
  for (int i = 0; i < 16; i++)
    qreg[i] = qkv[base + (size_t)(wave * 16 + i) * QKVLD + lane];

  float ksb[4];
#pragma unroll
  for (int j = 0; j < 4; j++) ksb[j] = Ksum[ksoff + j * 16 + fr];

  // ---- P0: coalesced row loads ----
  {
    const int rr  = tid >> 3;            // 0..31
    const int sg8 = (tid & 7) * 8;       // 0..56
#pragma unroll
    for (int p = 0; p < 2; p++) {
      const int t = p * 32 + rr;
      *(half8*)&kxh[t][sg8] =
          *(const half8*)(qkv + base + (size_t)t * QKVLD + 1024 + sg8);
      *(half8*)&Ph[t][64 + sg8] =
          *(const half8*)(qkv + base + (size_t)t * QKVLD + 2048 + sg8);
    }
  }
  // Sp^T rows (fp16, straight copy)
  {
    const int m  = tid >> 2;             // 0..63
    const int l0 = (tid & 3) * 16;       // 0,16,32,48
    *(half8*)&Bh[m][l0]     = *(const half8*)(KVp + m * 64 + l0);
    *(half8*)&Bh[m][l0 + 8] = *(const half8*)(KVp + m * 64 + l0 + 8);
  }
  __syncthreads();

  // ---- T: LDS transposes (b32 column reads, lane=col -> conflict-free) ----
  {
    const int l2  = (tid & 31) * 2;      // even column pair
    const int tg8 = (tid >> 5) * 8;      // 8-row group
    half8 k0, k1, v0, v1;
#pragma unroll
    for (int j = 0; j < 8; j++) {
      const int t = tg8 + j;
      half2v kk = *(const half2v*)&kxh[t][l2];
      k0[j] = kk[0]; k1[j] = kk[1];
      half2v vv = *(const half2v*)&Ph[t][64 + l2];
      v0[j] = vv[0]; v1[j] = vv[1];
    }
    *(half8*)&kxT[l2][tg8]          = k0;
    *(half8*)&kxT[l2 + 1][tg8]      = k1;
    *(half8*)&Bh[l2][64 + tg8]      = v0;
    *(half8*)&Bh[l2 + 1][64 + tg8]  = v1;
  }
  __syncthreads();

  // ---- P1: inclusive cumsum over t via tri-MFMA: kn = L . Kx ----
  {
    floatx4 kacc[4];
#pragma unroll
    for (int j = 0; j < 4; j++) kacc[j] = (floatx4){0.f, 0.f, 0.f, 0.f};
#pragma unroll
    for (int ks = 0; ks < 2; ks++) {
      half8 af;
#pragma unroll
      for (int j = 0; j < 8; j++)
        af[j] = (ks * 32 + fq * 8 + j) <= (wave * 16 + fr) ? (_Float16)1.0f
                                                           : (_Float16)0.0f;
#pragma unroll
      for (int j = 0; j < 4; j++) {
        half8 bf = *(const half8*)&kxT[j * 16 + fr][ks * 32 + fq * 8];
        kacc[j] = __builtin_amdgcn_mfma_f32_16x16x32_f16(af, bf, kacc[j], 0, 0, 0);
      }
    }
    __syncthreads();   // all kxT reads done -> safe to overwrite with kninv
#pragma unroll
    for (int j = 0; j < 4; j++)
#pragma unroll
      for (int r = 0; r < 4; r++)
        kxT[wave * 16 + fq * 4 + r][j * 16 + fr] =
            (_Float16)(QSC / (ksb[j] + kacc[j][r]));
  }
  // no barrier: P2 reads only this wave's own kninv strip

  // ---- P2: softmax * kninv -> Ph[:,0:64] (no-max variant) ----
#pragma unroll
  for (int i = 0; i < 16; i++) {
    const int t = wave * 16 + i;
    float e = __expf((float)qreg[i] * SCL);
    float s = wave_sum64(e);
    Ph[t][lane] = (_Float16)((e / s) * (float)kxT[t][lane]);
  }
  __syncthreads();

  // ---- P3: scores A = Qs . Kx^T (NT), causal mask, -> Ph[:,64:128] ----
  const int wm = (wave >> 1) * 32, wn = (wave & 1) * 32;
  {
    floatx4 a2[2][2];
#pragma unroll
    for (int mt = 0; mt < 2; mt++)
#pragma unroll
      for (int nt = 0; nt < 2; nt++) a2[mt][nt] = (floatx4){0.f, 0.f, 0.f, 0.f};
#pragma unroll
    for (int ks = 0; ks < 2; ks++) {
      half8 af[2], bf[2];
#pragma unroll
      for (int i = 0; i < 2; i++) {
        af[i] = *(const half8*)&Ph[wm + i * 16 + fr][ks * 32 + fq * 8];
        bf[i] = *(const half8*)&kxh[wn + i * 16 + fr][ks * 32 + fq * 8];
      }
#pragma unroll
      for (int mt = 0; mt < 2; mt++)
#pragma unroll
        for (int nt = 0; nt < 2; nt++)
          a2[mt][nt] = __builtin_amdgcn_mfma_f32_16x16x32_f16(af[mt], bf[nt], a2[mt][nt], 0, 0, 0);
    }
#pragma unroll
    for (int mt = 0; mt < 2; mt++)
#pragma unroll
      for (int nt = 0; nt < 2; nt++)
#pragma unroll
        for (int r = 0; r < 4; r++) {
          const int t = wm + mt * 16 + fq * 4 + r;
          const int s = wn + nt * 16 + fr;
          Ph[t][64 + s] = (_Float16)(s <= t ? a2[mt][nt][r] : 0.f);
        }
  }
  __syncthreads();

  // ---- P4: Y = [Qs|A] . [Sp^T|V^T]^T (NT, K=128); stage into kxh ----
  {
    floatx4 acc[2][2];
#pragma unroll
    for (int mt = 0; mt < 2; mt++)
#pragma unroll
      for (int nt = 0; nt < 2; nt++) acc[mt][nt] = (floatx4){0.f, 0.f, 0.f, 0.f};
#pragma unroll
    for (int ks = 0; ks < 4; ks++) {
      half8 af[2], bf[2];
#pragma unroll
      for (int i = 0; i < 2; i++) {
        af[i] = *(const half8*)&Ph[wm + i * 16 + fr][ks * 32 + fq * 8];
        bf[i] = *(const half8*)&Bh[wn + i * 16 + fr][ks * 32 + fq * 8];
      }
#pragma unroll
      for (int mt = 0; mt < 2; mt++)
#pragma unroll
        for (int nt = 0; nt < 2; nt++)
          acc[mt][nt] = __builtin_amdgcn_mfma_f32_16x16x32_f16(af[mt], bf[nt], acc[mt][nt], 0, 0, 0);
    }
#pragma unroll
    for (int mt = 0; mt < 2; mt++)
#pragma unroll
      for (int nt = 0; nt < 2; nt++)
#pragma unroll
        for (int r = 0; r < 4; r++)
          kxh[wm + mt * 16 + fq * 4 + r][wn + nt * 16 + fr] =
              (_Float16)(acc[mt][nt][r] * QSCI);
  }
  __syncthreads();

  // coalesced store: 4 threads cover one 128 B row
  {
    const int ty = tid >> 2, sg = (tid & 3) * 16;
    _Float16* yrow = Y + (size_t)(b * Tsz + c * CH + ty) * Dsz + h * 64 + sg;
    *(half8*)(yrow)     = *(const half8*)&kxh[ty][sg];
    *(half8*)(yrow + 8) = *(const half8*)&kxh[ty][sg + 8];
  }
}

// ---------------------------------------------------------------------------
extern "C" void kernel_launch(void* const* d_in, const int* in_sizes, int n_in,
                              void* d_out, int out_size, void* d_ws, size_t ws_size,
                              hipStream_t stream) {
  const float* x     = (const float*)d_in[0];   // (4,2048,1024)
  const float* w     = (const float*)d_in[1];   // (3072,1024)
  const float* w_out = (const float*)d_in[2];   // (1024,1024)
  float* out = (float*)d_out;                   // (4,2048,1024)

  _Float16* xh   = (_Float16*)d_ws;                  // 8192*1024
  _Float16* Yh   = xh;                               // alias (xh dead after GEMM1)
  _Float16* wh   = xh + (size_t)8192 * 1024;         // 3072*1024
  _Float16* woT  = wh + (size_t)3072 * 1024;         // 1024*1024
  _Float16* qkvh = woT + (size_t)1024 * 1024;        // 8192*3072 fp16 (k-region = kexp)
  _Float16* KV   = qkvh + (size_t)8192 * 3072;       // 64*32*4096 fp16 (S^T/prefix)
  float* Ksum = (float*)(KV + (size_t)BHsz * NCH * 4096);  // 64*32*64 fp32

  // 0) fused dtype prep
  prep<<<12288, 256, 0, stream>>>(x, xh, w, wh, w_out, woT);

  // 1) qkv = x @ w.T (fp16 out, kexp fused for k-columns) — 256² 8-thin-phase
  qkv_gemm8<<<384, 512, 0, stream>>>(xh, wh, qkvh);

  // 2) chunked scan (KV fp16)
  chunk_kv<<<2048, 256, 0, stream>>>(qkvh, KV, Ksum);
  prefix_kern<<<512, 256, 0, stream>>>(KV, Ksum);
  chunk_y<<<dim3(BHsz, NCH), 256, 0, stream>>>(qkvh, KV, Ksum, Yh);

  // 3) out = y @ w_out — dbuf counted-vmcnt 128² schedule
  gemm2<<<512, 256, 0, stream>>>(Yh, woT, out);
}